// Round 4
// baseline (140.783 us; speedup 1.0000x reference)
//
#include <hip/hip_runtime.h>
#include <math.h>

// B=2, HD=4, H=W=128, KSIZE=7 (K=49), NSP=9, S=64
#define BN   2
#define HDN  4
#define HN   128
#define WN   128
#define KS   7
#define KK   49
#define NSPN 9
#define SN   64
#define TPB  128     // 2 autonomous waves; each owns 16 pixels x 4 heads
#define CH   788     // albuf chunk stride (dwords): 784 data + 4 pad
#define PIXSTR 60    // gather buf pixel stride (dwords), 16B-aligned

// v6 = v5's line-touch-minimal plan with spill-proof codegen. v5's rocprof
// showed +113MB scratch traffic (WRITE 110 vs 26 compulsory): float4 ARRAYS
// filled via memcpy (areg[4][4], gst[4]) were demoted to scratch (SROA
// failure), VGPR stuck at 104. v6: all staged values live in NAMED float4
// scalars; attn/out use provably-16B-aligned plain float4 ops (base is a
// multiple of 49*32 dwords); memcpy only for unaligned gather loads into
// named q0..q3. Zero __syncthreads: all LDS wave-private, DS in-order.
__global__ __launch_bounds__(TPB, 2) void attn_rw6(
    const float* __restrict__ attn,
    const float* __restrict__ sims,
    const int*   __restrict__ sinds,
    float*       __restrict__ out)
{
    __shared__ __align__(16) float albuf[2][4 * CH];      // per-wave 12.6 KB
    __shared__ __align__(16) int   gbuf[2][16 * NSPN];    // per-wave sinds

    const int t    = threadIdx.x;
    const int lane = t & 63;
    const int wv   = t >> 6;
    const int bx   = blockIdx.x;
    const int wseg = bx & 3;
    const int hh   = (bx >> 2) & 127;
    const int b    = bx >> 9;
    const int ww0  = wseg * 32 + wv * 16;   // wave's first absolute column

    const int pixL = lane >> 2;             // 0..15 (compute mapping)
    const int hd   = lane & 3;

    const float* simsB = sims + ((size_t)b << 20);
    int hs = hh - 3; hs = max(0, min(HN - KS, hs));
    const int dr = hh - hs;                 // 0..6, block-uniform

    float* al = albuf[wv];
    int*   gl = gbuf[wv];

    // ---------- sinds first (1 coalesced load, named reg) ----------
    int4 sreg = make_int4(0, 0, 0, 0);
    const int* ssrc = sinds + ((b * HN + hh) * WN + ww0) * NSPN;
    if (lane < 36) __builtin_memcpy(&sreg, ssrc + lane * 4, 16);

    // ---------- attn staging: 2-deep pipeline, named float4, aligned ----------
    const size_t cstride = (size_t)HN * WN * KK;                       // hd-plane stride (dwords)
    const size_t abase0  = ((((size_t)b * HDN) * HN + hh) * WN + ww0) * (size_t)KK;
    const float* a0p = attn + abase0;                                  // 16B-aligned (49*32*N dwords)

    float4 A0, A1, A2, A3, B0, B1, B2, B3;
    auto ldc = [&](int c, float4& x0, float4& x1, float4& x2, float4& x3) {
        const float* g = a0p + (size_t)c * cstride;
        x0 = *(const float4*)(g + lane * 4);
        x1 = *(const float4*)(g + 256 + lane * 4);
        x2 = *(const float4*)(g + 512 + lane * 4);
        x3 = make_float4(0.f, 0.f, 0.f, 0.f);
        if (lane < 4) x3 = *(const float4*)(g + 768 + lane * 4);
    };
    auto stc = [&](int c, float4 x0, float4 x1, float4 x2, float4 x3) {
        float* d = al + c * CH;
        *(float4*)(d + lane * 4) = x0;
        *(float4*)(d + 256 + lane * 4) = x1;
        *(float4*)(d + 512 + lane * 4) = x2;
        if (lane < 4) *(float4*)(d + 768 + lane * 4) = x3;
    };

    ldc(0, A0, A1, A2, A3);
    ldc(1, B0, B1, B2, B3);
    if (lane < 36) *(int4*)(gl + lane * 4) = sreg;   // publish sinds (wave-private)
    stc(0, A0, A1, A2, A3);
    ldc(2, A0, A1, A2, A3);
    stc(1, B0, B1, B2, B3);
    ldc(3, B0, B1, B2, B3);
    stc(2, A0, A1, A2, A3);
    stc(3, B0, B1, B2, B3);

    // ---------- gather lane constants ----------
    int grp = lane / 14; grp = min(grp, 3);
    const int  cp    = lane - grp * 14;
    const int  grow  = min(cp >> 1, 6);              // 0..6 (clamped for inactive lanes)
    const int  ghalf = cp & 1;                       // 0: cols 0-3, 1: cols 3-6
    const bool gact  = lane < 56;
    int pixs[4], wss[4];
    #pragma unroll
    for (int i = 0; i < 4; ++i) {
        pixs[i] = 4 * i + grp;
        wss[i]  = max(0, min(WN - KS, ww0 + pixs[i] - 3));
    }
    const int rowoff = (hs + grow) * WN + ghalf * 3;

    float4 q0, q1, q2, q3;                           // named: never spills
    auto gissue = [&](int sp) {
        int g0 = gl[pixs[0] * NSPN + sp];
        int g1 = gl[pixs[1] * NSPN + sp];
        int g2 = gl[pixs[2] * NSPN + sp];
        int g3 = gl[pixs[3] * NSPN + sp];
        if (gact) {
            __builtin_memcpy(&q0, simsB + ((size_t)g0 << 14) + rowoff + wss[0], 16);
            __builtin_memcpy(&q1, simsB + ((size_t)g1 << 14) + rowoff + wss[1], 16);
            __builtin_memcpy(&q2, simsB + ((size_t)g2 << 14) + rowoff + wss[2], 16);
            __builtin_memcpy(&q3, simsB + ((size_t)g3 << 14) + rowoff + wss[3], 16);
        }
    };
    auto gwrite = [&](int buf) {
        float* pb = al + buf * 16 * PIXSTR;
        if (gact) {
            *(float4*)(pb + pixs[0] * PIXSTR + grow * 8 + ghalf * 4) = q0;
            *(float4*)(pb + pixs[1] * PIXSTR + grow * 8 + ghalf * 4) = q1;
            *(float4*)(pb + pixs[2] * PIXSTR + grow * 8 + ghalf * 4) = q2;
            *(float4*)(pb + pixs[3] * PIXSTR + grow * 8 + ghalf * 4) = q3;
        }
    };

    gissue(0);                                       // sp0 loads in flight early

    // ---------- redistribute attn to a[49] (LDS, ~2-way banks) ----------
    const int abase = hd * CH + pixL * KK;
    float a[KK];
    #pragma unroll
    for (int k = 0; k < KK; ++k) a[k] = al[abase + k];

    // softmax (pure VALU - covers gather(0) flight)
    {
        float m0 = a[0], m1 = a[1], m2 = a[2], m3 = a[3];
        #pragma unroll
        for (int k = 4; k < KK; k += 4) {
            m0 = fmaxf(m0, a[k]);
            if (k + 1 < KK) m1 = fmaxf(m1, a[k + 1]);
            if (k + 2 < KK) m2 = fmaxf(m2, a[k + 2]);
            if (k + 3 < KK) m3 = fmaxf(m3, a[k + 3]);
        }
        float m = fmaxf(fmaxf(m0, m1), fmaxf(m2, m3));
        #pragma unroll
        for (int k = 0; k < KK; ++k) a[k] = __expf(a[k] - m);
    }

    gwrite(0);                                       // after a[] reads (in-order DS)

    // pi location inside own patch: row dr, col dc (slot bump past dup col 3)
    const int ws_s  = max(0, min(WN - KS, ww0 + pixL - 3));
    const int dc    = ww0 + pixL - ws_s;             // 0..6
    const int dcs   = dc + (dc > 3 ? 1 : 0);
    const int pioff = pixL * PIXSTR + dr * 8 + dcs;

    float acc[KK];
    #pragma unroll
    for (int k = 0; k < KK; ++k) acc[k] = 0.0f;

    #define P(k) p[(k) / KS][(k) % KS]

    for (int sp = 0; sp < NSPN; ++sp) {
        const int buf = sp & 1;
        if (sp + 1 < NSPN) gissue(sp + 1);           // next plane in flight

        const float* prow = al + buf * 16 * PIXSTR + pixL * PIXSTR;
        float p[KS][KS];
        #pragma unroll
        for (int r = 0; r < KS; ++r) {
            float4 lo = *(const float4*)(prow + r * 8);      // cols 0-3
            float4 hi = *(const float4*)(prow + r * 8 + 4);  // cols 3-6
            p[r][0] = lo.x; p[r][1] = lo.y; p[r][2] = lo.z; p[r][3] = lo.w;
            p[r][4] = hi.y; p[r][5] = hi.z; p[r][6] = hi.w;
        }
        float pi = al[buf * 16 * PIXSTR + pioff];

        // denom: 4-way split FMA chains
        float d0 = 0.f, d1 = 0.f, d2 = 0.f, d3 = 0.f;
        #pragma unroll
        for (int k = 0; k < 48; k += 4) {
            d0 = fmaf(a[k + 0], P(k + 0), d0);
            d1 = fmaf(a[k + 1], P(k + 1), d1);
            d2 = fmaf(a[k + 2], P(k + 2), d2);
            d3 = fmaf(a[k + 3], P(k + 3), d3);
        }
        d0 = fmaf(a[48], P(48), d0);
        float d    = (d0 + d1) + (d2 + d3);
        float coef = pi * __builtin_amdgcn_rcpf(d + 1e-10f);

        #pragma unroll
        for (int k = 0; k < KK; ++k) acc[k] = fmaf(coef, P(k), acc[k]);

        if (sp + 1 < NSPN) gwrite(buf ^ 1);          // in-order DS; no barrier
    }
    #undef P

    // ---------- out: regs -> LDS (attn layout) -> aligned coalesced stores ----------
    #pragma unroll
    for (int k = 0; k < KK; ++k) al[abase + k] = a[k] * acc[k];

    #pragma unroll
    for (int c = 0; c < 4; ++c) {
        float*       gd = out + abase0 + (size_t)c * cstride;
        const float* sc = al + c * CH;
        float4 y0 = *(const float4*)(sc + lane * 4);
        float4 y1 = *(const float4*)(sc + 256 + lane * 4);
        float4 y2 = *(const float4*)(sc + 512 + lane * 4);
        *(float4*)(gd + lane * 4) = y0;
        *(float4*)(gd + 256 + lane * 4) = y1;
        *(float4*)(gd + 512 + lane * 4) = y2;
        if (lane < 4) {
            float4 y3 = *(const float4*)(sc + 768 + lane * 4);
            *(float4*)(gd + 768 + lane * 4) = y3;
        }
    }
}

extern "C" void kernel_launch(void* const* d_in, const int* in_sizes, int n_in,
                              void* d_out, int out_size, void* d_ws, size_t ws_size,
                              hipStream_t stream) {
    const float* attn  = (const float*)d_in[0];
    const float* sims  = (const float*)d_in[1];
    const int*   sinds = (const int*)d_in[2];
    float*       outp  = (float*)d_out;

    // blocks: b(2) x hh(128) x wseg(4) = 1024, 2 autonomous waves each
    const int blocks = BN * HN * (WN / 32);
    attn_rw6<<<blocks, TPB, 0, stream>>>(attn, sims, sinds, outp);
}

// Round 6
// 100.083 us; speedup vs baseline: 1.4067x; 1.4067x over previous
//
#include <hip/hip_runtime.h>
#include <math.h>

// B=2, HD=4, H=W=128, KSIZE=7 (K=49), NSP=9, S=64
#define BN   2
#define HDN  4
#define HN   128
#define WN   128
#define KS   7
#define KK   49
#define NSPN 9
#define TPB  128     // 2 fully-autonomous waves; wave owns 16 pixels x 4 heads
#define PROW 52      // patch row stride (dwords)
#define PBUF 832     // 16*PROW, one gather buffer
#define STG  3136    // 4 planes x 784 dwords, per-wave staging (attn in / out)
#define WREG (STG + 2 * PBUF)   // 4800 dwords per wave

// Compiler-only memory fence: orders LDS/global ops at IR+MIR level, emits
// nothing. Needed because cross-lane LDS exchange without a barrier is only
// HW-safe (same-wave DS is in-order); the COMPILER may reorder LDS ops that
// don't alias per-thread (v7's failure: chunked stage reuse got reordered).
#define CFENCE() asm volatile("" ::: "memory")

// v8 = v7's memory plan (coalesced attn/out via LDS staging, pi-from-patch,
// zero __syncthreads, v3-proven gather codegen) + explicit compiler fences at
// every cross-lane LDS publish->consume point + disjoint staging region (all
// 4 planes staged at once; no read/overwrite chunk reuse). Stage loads are
// issued BEFORE gissue(0) so stage ds_writes wait (vmcnt) only on their own
// older loads, keeping the 16 scattered gather loads in flight under softmax.
__global__ __launch_bounds__(TPB, 2) void attn_rw8(
    const float* __restrict__ attn,
    const float* __restrict__ sims,
    const int*   __restrict__ sinds,
    float*       __restrict__ out)
{
    __shared__ __align__(16) float smem[2 * WREG];      // 38.4 KB
    __shared__ int g_lds[2][16 * NSPN];                 // 1.2 KB

    const int t    = threadIdx.x;
    const int lane = t & 63;
    const int wv   = t >> 6;
    const int bx   = blockIdx.x;
    const int wseg = bx & 3;
    const int hh   = (bx >> 2) & 127;
    const int b    = bx >> 9;
    const int ww0  = wseg * 32 + wv * 16;   // wave's first absolute column

    const int pixL = lane >> 2;             // 0..15 (compute mapping)
    const int hd   = lane & 3;

    const float* simsB = sims + ((size_t)b << 20);
    int hs = hh - 3; hs = max(0, min(HN - KS, hs));
    const int dr = hh - hs;                 // 0..6, block-uniform

    float* stg = smem + wv * WREG;          // [0..3135] staging
    float* pb  = stg + STG;                 // [2][832] gather buffers
    int*   gl  = g_lds[wv];

    // ---- sinds: wave-private 144 ints, one coalesced int4 round ----
    {
        const int* ssrc = sinds + ((b * HN + hh) * WN + ww0) * NSPN;
        if (lane < 36) {
            int4 s;
            __builtin_memcpy(&s, ssrc + lane * 4, 16);
            *(int4*)(gl + lane * 4) = s;
        }
    }
    CFENCE();                               // gl published before gissue reads it

    // ---- attn stage LOADS: all 16 float4 first (named scalars) ----
    const size_t hwk   = (size_t)HN * WN * KK;
    const size_t pbase = (size_t)(hh * WN + ww0) * KK;   // 16B-aligned
    const float* aB    = attn + (size_t)b * HDN * hwk + pbase;

    float4 s00,s01,s02,s03, s10,s11,s12,s13, s20,s21,s22,s23, s30,s31,s32,s33;
#define LDP(c, v0, v1, v2, v3) { \
        const float* g_ = aB + (size_t)(c) * hwk; \
        v0 = *(const float4*)(g_ + lane * 4); \
        v1 = *(const float4*)(g_ + 256 + lane * 4); \
        v2 = *(const float4*)(g_ + 512 + lane * 4); \
        v3 = make_float4(0.f, 0.f, 0.f, 0.f); \
        if (lane < 4) v3 = *(const float4*)(g_ + 768 + lane * 4); }
    LDP(0, s00, s01, s02, s03)
    LDP(1, s10, s11, s12, s13)
    LDP(2, s20, s21, s22, s23)
    LDP(3, s30, s31, s32, s33)
#undef LDP

    // ---- gather constants + issue sp0 (after stage loads: vmcnt ordering) ----
    const int  gki     = lane / KS;
    const int  gkj     = lane - gki * KS;
    const bool gact    = lane < KK;
    const int  laneoff = gact ? (gki * WN + gkj) : 0;

    float gr[16];
    auto gissue = [&](int sp) {
        int gv = 0;
        if (lane < 16) gv = gl[lane * NSPN + sp];
        #pragma unroll
        for (int i = 0; i < 16; ++i) {
            int g  = __builtin_amdgcn_readlane(gv, i);       // scalar g per pixel
            int ws = ww0 + i - 3; ws = max(0, min(WN - KS, ws));
            if (gact) gr[i] = simsB[((size_t)g << 14) + hs * WN + ws + laneoff];
        }
    };
    auto gstore = [&](int buf) {
        if (gact) {
            #pragma unroll
            for (int i = 0; i < 16; ++i)
                pb[buf * PBUF + i * PROW + lane] = gr[i];
        }
    };

    gissue(0);                               // 16 scattered loads in flight

    // ---- attn stage STORES (wait only on their own older loads) ----
#define STP(c, v0, v1, v2, v3) { \
        float* d_ = stg + (c) * 784; \
        *(float4*)(d_ + lane * 4) = v0; \
        *(float4*)(d_ + 256 + lane * 4) = v1; \
        *(float4*)(d_ + 512 + lane * 4) = v2; \
        if (lane < 4) *(float4*)(d_ + 768 + lane * 4) = v3; }
    STP(0, s00, s01, s02, s03)
    STP(1, s10, s11, s12, s13)
    STP(2, s20, s21, s22, s23)
    STP(3, s30, s31, s32, s33)
#undef STP
    CFENCE();                                // cross-lane RAW: stage writes -> a[] reads

    // ---- redistribute attn to a[49] (stride-49 scalar: 2-way banks = free) ----
    const int ab = hd * 784 + pixL * KK;
    float a[KK];
    #pragma unroll
    for (int k = 0; k < KK; ++k) a[k] = stg[ab + k];

    // softmax (pure VALU - covers gather(0) flight)
    {
        float m0 = a[0], m1 = a[1], m2 = a[2], m3 = a[3];
        #pragma unroll
        for (int k = 4; k < KK; k += 4) {
            m0 = fmaxf(m0, a[k]);
            if (k + 1 < KK) m1 = fmaxf(m1, a[k + 1]);
            if (k + 2 < KK) m2 = fmaxf(m2, a[k + 2]);
            if (k + 3 < KK) m3 = fmaxf(m3, a[k + 3]);
        }
        float m = fmaxf(fmaxf(m0, m1), fmaxf(m2, m3));
        #pragma unroll
        for (int k = 0; k < KK; ++k) a[k] = __expf(a[k] - m);
    }

    gstore(0);                               // pb disjoint from stg: no extra fence

    // pi = patch[dr][dc] of own pixel (center similarity, free from gather)
    const int wabs  = ww0 + pixL;
    const int wsp   = max(0, min(WN - KS, wabs - 3));
    const int dc    = wabs - wsp;            // 0..6
    const int pioff = pixL * PROW + dr * KS + dc;

    float acc[KK];
    #pragma unroll
    for (int k = 0; k < KK; ++k) acc[k] = 0.0f;

    for (int sp = 0; sp < NSPN; ++sp) {
        const int buf = sp & 1;
        if (sp + 1 < NSPN) gissue(sp + 1);   // next plane's loads in flight
        CFENCE();                            // RAW: gstore(prev)->p reads; WAR: prev reads->gstore below

        // p row: 12 x b128 + 1 (4 hd-lanes broadcast, 16 pixL 2-way = free)
        float p[KK];
        const float* prow = pb + buf * PBUF + pixL * PROW;
        #pragma unroll
        for (int k4 = 0; k4 < 12; ++k4) {
            float4 v = *(const float4*)(prow + k4 * 4);
            p[k4 * 4 + 0] = v.x; p[k4 * 4 + 1] = v.y;
            p[k4 * 4 + 2] = v.z; p[k4 * 4 + 3] = v.w;
        }
        p[48] = prow[48];

        // denom: 4-way split FMA chains
        float d0 = 0.f, d1 = 0.f, d2 = 0.f, d3 = 0.f;
        #pragma unroll
        for (int k = 0; k < 48; k += 4) {
            d0 = fmaf(a[k + 0], p[k + 0], d0);
            d1 = fmaf(a[k + 1], p[k + 1], d1);
            d2 = fmaf(a[k + 2], p[k + 2], d2);
            d3 = fmaf(a[k + 3], p[k + 3], d3);
        }
        d0 = fmaf(a[48], p[48], d0);
        float d = (d0 + d1) + (d2 + d3);

        float pi   = pb[buf * PBUF + pioff];
        float coef = pi * __builtin_amdgcn_rcpf(d + 1e-10f);

        #pragma unroll
        for (int k = 0; k < KK; ++k) acc[k] = fmaf(coef, p[k], acc[k]);

        if (sp + 1 < NSPN) gstore(buf ^ 1);  // in-wave order; no barrier
    }

    // ---- out: scalar LDS stage (same addrs as a[]-reads: auto-ordered) ----
    #pragma unroll
    for (int k = 0; k < KK; ++k) stg[ab + k] = a[k] * acc[k];
    CFENCE();                                // cross-lane RAW: out writes -> float4 reads

    float* oB = out + (size_t)b * HDN * hwk + pbase;
    #pragma unroll
    for (int c = 0; c < 4; ++c) {
        const float* s_ = stg + c * 784;
        float*       o_ = oB + (size_t)c * hwk;
        float4 z0 = *(const float4*)(s_ + lane * 4);
        float4 z1 = *(const float4*)(s_ + 256 + lane * 4);
        float4 z2 = *(const float4*)(s_ + 512 + lane * 4);
        *(float4*)(o_ + lane * 4) = z0;
        *(float4*)(o_ + 256 + lane * 4) = z1;
        *(float4*)(o_ + 512 + lane * 4) = z2;
        if (lane < 4) {
            float4 z3 = *(const float4*)(s_ + 768 + lane * 4);
            *(float4*)(o_ + 768 + lane * 4) = z3;
        }
    }
}

extern "C" void kernel_launch(void* const* d_in, const int* in_sizes, int n_in,
                              void* d_out, int out_size, void* d_ws, size_t ws_size,
                              hipStream_t stream) {
    const float* attn  = (const float*)d_in[0];
    const float* sims  = (const float*)d_in[1];
    const int*   sinds = (const int*)d_in[2];
    float*       outp  = (float*)d_out;

    // blocks: b(2) x hh(128) x wseg(4) = 1024, 2 autonomous waves each
    const int blocks = BN * HN * (WN / 32);
    attn_rw8<<<blocks, TPB, 0, stream>>>(attn, sims, sinds, outp);
}

// Round 7
// 95.492 us; speedup vs baseline: 1.4743x; 1.0481x over previous
//
#include <hip/hip_runtime.h>
#include <math.h>

// B=2, HD=4, H=W=128, KSIZE=7 (K=49), NSP=9, S=64
#define BN   2
#define HDN  4
#define HN   128
#define WN   128
#define KS   7
#define KK   49
#define NSPN 9
#define TPB  128     // 2 fully-autonomous waves; wave owns 16 pixels x 4 heads
#define PIXSTR 60    // gather-buf pixel stride (dwords): 16B-aligned, 2-way banks
#define PBUF (16 * PIXSTR)      // 960 dwords per gather buffer
#define STG  3136    // 4 planes x 784 dwords, per-wave staging (attn in / out)
                     // gather bufs [2][PBUF] OVERLAY stg[0..1919] (disjoint lifetimes)

// Compiler-only memory fence (orders LDS ops the compiler can't see alias
// cross-lane; emits nothing). v8-validated discipline.
#define CFENCE() asm volatile("" ::: "memory")

// v9 = v8 skeleton (coalesced attn/out LDS staging, pi-from-patch, zero
// __syncthreads, CFENCE discipline) + v5's wide gather: 4 patches per VMEM
// instruction (14 lanes/patch: 7 rows x 2 overlapping dwordx4 covering cols
// 0-3/3-6), in-flight values in NAMED q0..q3 float4 (16 VGPR, = old gr[16];
// v5/v6's spill came from memcpy'd ARRAYS, avoided here). Gather VMEM instrs
// 144 -> 36 per wave: the TA address-processing term (now ~dominant) /4.
// Gather buffers overlaid on the staging region: LDS 39.6 -> 26.3 KB.
__global__ __launch_bounds__(TPB, 2) void attn_rw9(
    const float* __restrict__ attn,
    const float* __restrict__ sims,
    const int*   __restrict__ sinds,
    float*       __restrict__ out)
{
    __shared__ __align__(16) float smem[2 * STG];       // 25.1 KB
    __shared__ int g_lds[2][16 * NSPN];                 // 1.2 KB

    const int t    = threadIdx.x;
    const int lane = t & 63;
    const int wv   = t >> 6;
    const int bx   = blockIdx.x;
    const int wseg = bx & 3;
    const int hh   = (bx >> 2) & 127;
    const int b    = bx >> 9;
    const int ww0  = wseg * 32 + wv * 16;   // wave's first absolute column

    const int pixL = lane >> 2;             // 0..15 (compute mapping)
    const int hd   = lane & 3;

    const float* simsB = sims + ((size_t)b << 20);
    int hs = hh - 3; hs = max(0, min(HN - KS, hs));
    const int dr = hh - hs;                 // 0..6, block-uniform

    float* stg = smem + wv * STG;           // wave-private staging
    float* pb  = stg;                       // gather bufs overlay stg[0..1919]
    int*   gl  = g_lds[wv];

    // ---- sinds: wave-private 144 ints, one coalesced int4 round ----
    {
        const int* ssrc = sinds + ((b * HN + hh) * WN + ww0) * NSPN;
        if (lane < 36) {
            int4 s;
            __builtin_memcpy(&s, ssrc + lane * 4, 16);
            *(int4*)(gl + lane * 4) = s;
        }
    }
    CFENCE();                               // gl published before gissue reads it

    // ---- attn stage LOADS: all 16 float4 first (named scalars) ----
    const size_t hwk   = (size_t)HN * WN * KK;
    const size_t pbase = (size_t)(hh * WN + ww0) * KK;   // 16B-aligned
    const float* aB    = attn + (size_t)b * HDN * hwk + pbase;

    float4 s00,s01,s02,s03, s10,s11,s12,s13, s20,s21,s22,s23, s30,s31,s32,s33;
#define LDP(c, v0, v1, v2, v3) { \
        const float* g_ = aB + (size_t)(c) * hwk; \
        v0 = *(const float4*)(g_ + lane * 4); \
        v1 = *(const float4*)(g_ + 256 + lane * 4); \
        v2 = *(const float4*)(g_ + 512 + lane * 4); \
        v3 = make_float4(0.f, 0.f, 0.f, 0.f); \
        if (lane < 4) v3 = *(const float4*)(g_ + 768 + lane * 4); }
    LDP(0, s00, s01, s02, s03)
    LDP(1, s10, s11, s12, s13)
    LDP(2, s20, s21, s22, s23)
    LDP(3, s30, s31, s32, s33)
#undef LDP

    // ---- wide-gather lane constants (4 patches / instruction) ----
    const int  grp   = min(lane / 14, 3);   // patch slot within instr
    const int  cp    = lane - grp * 14;     // 0..13 active
    const int  grow  = min(cp >> 1, 6);     // row 0..6
    const int  ghalf = cp & 1;              // 0: cols 0-3, 1: cols 3-6
    const bool gact  = lane < 56;
    int pixs[4], wss[4];
    #pragma unroll
    for (int i = 0; i < 4; ++i) {
        pixs[i] = 4 * i + grp;
        wss[i]  = max(0, min(WN - KS, ww0 + pixs[i] - 3));
    }
    const int rowoff = (hs + grow) * WN + ghalf * 3;

    float4 q0, q1, q2, q3;                  // named in-flight regs: never spill
    auto gissue = [&](int sp) {
        int g0 = gl[pixs[0] * NSPN + sp];   // 4-lane broadcast reads
        int g1 = gl[pixs[1] * NSPN + sp];
        int g2 = gl[pixs[2] * NSPN + sp];
        int g3 = gl[pixs[3] * NSPN + sp];
        if (gact) {
            __builtin_memcpy(&q0, simsB + ((size_t)g0 << 14) + rowoff + wss[0], 16);
            __builtin_memcpy(&q1, simsB + ((size_t)g1 << 14) + rowoff + wss[1], 16);
            __builtin_memcpy(&q2, simsB + ((size_t)g2 << 14) + rowoff + wss[2], 16);
            __builtin_memcpy(&q3, simsB + ((size_t)g3 << 14) + rowoff + wss[3], 16);
        }
    };
    auto gstore = [&](int buf) {
        float* d = pb + buf * PBUF;
        if (gact) {
            *(float4*)(d + pixs[0] * PIXSTR + grow * 8 + ghalf * 4) = q0;
            *(float4*)(d + pixs[1] * PIXSTR + grow * 8 + ghalf * 4) = q1;
            *(float4*)(d + pixs[2] * PIXSTR + grow * 8 + ghalf * 4) = q2;
            *(float4*)(d + pixs[3] * PIXSTR + grow * 8 + ghalf * 4) = q3;
        }
    };

    gissue(0);                              // 4 scattered dwordx4 in flight

    // ---- attn stage STORES (vmcnt waits only on their own older loads) ----
#define STP(c, v0, v1, v2, v3) { \
        float* d_ = stg + (c) * 784; \
        *(float4*)(d_ + lane * 4) = v0; \
        *(float4*)(d_ + 256 + lane * 4) = v1; \
        *(float4*)(d_ + 512 + lane * 4) = v2; \
        if (lane < 4) *(float4*)(d_ + 768 + lane * 4) = v3; }
    STP(0, s00, s01, s02, s03)
    STP(1, s10, s11, s12, s13)
    STP(2, s20, s21, s22, s23)
    STP(3, s30, s31, s32, s33)
#undef STP
    CFENCE();                               // cross-lane RAW: stage writes -> a[] reads

    // ---- redistribute attn to a[49] (stride-49 scalar: ~2-way banks) ----
    const int ab = hd * 784 + pixL * KK;
    float a[KK];
    #pragma unroll
    for (int k = 0; k < KK; ++k) a[k] = stg[ab + k];

    // softmax (pure VALU - covers gather(0) flight)
    {
        float m0 = a[0], m1 = a[1], m2 = a[2], m3 = a[3];
        #pragma unroll
        for (int k = 4; k < KK; k += 4) {
            m0 = fmaxf(m0, a[k]);
            if (k + 1 < KK) m1 = fmaxf(m1, a[k + 1]);
            if (k + 2 < KK) m2 = fmaxf(m2, a[k + 2]);
            if (k + 3 < KK) m3 = fmaxf(m3, a[k + 3]);
        }
        float m = fmaxf(fmaxf(m0, m1), fmaxf(m2, m3));
        #pragma unroll
        for (int k = 0; k < KK; ++k) a[k] = __expf(a[k] - m);
    }
    CFENCE();                               // cross-lane WAR: a[] reads -> gstore(0) overlay write

    gstore(0);                              // overwrites stg[0..959] (staging now dead)

    // pi = patch[dr][dc] of own pixel; slot skips dup col 3 (hi.x == lo.w)
    const int wabs  = ww0 + pixL;
    const int wsp   = max(0, min(WN - KS, wabs - 3));
    const int dc    = wabs - wsp;           // 0..6
    const int dcs   = dc + (dc > 3 ? 1 : 0);
    const int pioff = pixL * PIXSTR + dr * 8 + dcs;

    float acc[KK];
    #pragma unroll
    for (int k = 0; k < KK; ++k) acc[k] = 0.0f;

    #define P(k) p[(k) / KS][(k) % KS]

    for (int sp = 0; sp < NSPN; ++sp) {
        const int buf = sp & 1;
        if (sp + 1 < NSPN) gissue(sp + 1);  // next plane's 4 loads in flight
        CFENCE();                           // RAW: gstore(prev) -> p reads; WAR: reads -> gstore below

        // p patch: 14 x b128 (lo/hi per row); 4 hd-lanes broadcast, pixL 2-way
        float p[KS][KS];
        const float* prow = pb + buf * PBUF + pixL * PIXSTR;
        #pragma unroll
        for (int r = 0; r < KS; ++r) {
            float4 lo = *(const float4*)(prow + r * 8);      // cols 0-3
            float4 hi = *(const float4*)(prow + r * 8 + 4);  // cols 3-6
            p[r][0] = lo.x; p[r][1] = lo.y; p[r][2] = lo.z; p[r][3] = lo.w;
            p[r][4] = hi.y; p[r][5] = hi.z; p[r][6] = hi.w;
        }

        // denom: 4-way split FMA chains
        float d0 = 0.f, d1 = 0.f, d2 = 0.f, d3 = 0.f;
        #pragma unroll
        for (int k = 0; k < 48; k += 4) {
            d0 = fmaf(a[k + 0], P(k + 0), d0);
            d1 = fmaf(a[k + 1], P(k + 1), d1);
            d2 = fmaf(a[k + 2], P(k + 2), d2);
            d3 = fmaf(a[k + 3], P(k + 3), d3);
        }
        d0 = fmaf(a[48], P(48), d0);
        float d = (d0 + d1) + (d2 + d3);

        float pi   = pb[buf * PBUF + pioff];
        float coef = pi * __builtin_amdgcn_rcpf(d + 1e-10f);

        #pragma unroll
        for (int k = 0; k < KK; ++k) acc[k] = fmaf(coef, P(k), acc[k]);

        if (sp + 1 < NSPN) gstore(buf ^ 1); // in-wave order; no barrier
    }
    #undef P

    // ---- out: scalar LDS stage (overwrites gather bufs) -> float4 stores ----
    CFENCE();                               // cross-lane WAR: last p reads -> out-stage writes
    #pragma unroll
    for (int k = 0; k < KK; ++k) stg[ab + k] = a[k] * acc[k];
    CFENCE();                               // cross-lane RAW: out writes -> float4 reads

    float* oB = out + (size_t)b * HDN * hwk + pbase;
    #pragma unroll
    for (int c = 0; c < 4; ++c) {
        const float* s_ = stg + c * 784;
        float*       o_ = oB + (size_t)c * hwk;
        float4 z0 = *(const float4*)(s_ + lane * 4);
        float4 z1 = *(const float4*)(s_ + 256 + lane * 4);
        float4 z2 = *(const float4*)(s_ + 512 + lane * 4);
        *(float4*)(o_ + lane * 4) = z0;
        *(float4*)(o_ + 256 + lane * 4) = z1;
        *(float4*)(o_ + 512 + lane * 4) = z2;
        if (lane < 4) {
            float4 z3 = *(const float4*)(s_ + 768 + lane * 4);
            *(float4*)(o_ + 768 + lane * 4) = z3;
        }
    }
}

extern "C" void kernel_launch(void* const* d_in, const int* in_sizes, int n_in,
                              void* d_out, int out_size, void* d_ws, size_t ws_size,
                              hipStream_t stream) {
    const float* attn  = (const float*)d_in[0];
    const float* sims  = (const float*)d_in[1];
    const int*   sinds = (const int*)d_in[2];
    float*       outp  = (float*)d_out;

    // blocks: b(2) x hh(128) x wseg(4) = 1024, 2 autonomous waves each
    const int blocks = BN * HN * (WN / 32);
    attn_rw9<<<blocks, TPB, 0, stream>>>(attn, sims, sinds, outp);
}